// Round 14
// baseline (67.801 us; speedup 1.0000x reference)
//
#include <hip/hip_runtime.h>
#include <stdint.h>

#define NREG   20
#define EDIM   768
#define DVOL   64
#define HVOL   512
#define WVOL   512
#define HW_    (HVOL * WVOL)
#define DHW_   (DVOL * HVOL * WVOL)
#define NPATCH 16384
#define BTOT   2
#define PROTO_N (NREG * EDIM)            // 15360
#define RF_N    (BTOT * PROTO_N)         // 30720 floats (output 0)
#define TOTAL_PATCHES (BTOT * NPATCH)    // 32768
#define NBUCKET 1024                     // 2 b x 32 zbins x 16 ybins
#define ZQN    16                        // z-quads per batch

#define SORT_BLOCKS  16
#define BUILD_BLOCKS 512
#define K1_BLOCKS    (SORT_BLOCKS + BUILD_BLOCKS)

// ---- workspace layout (u32 words) -----------------------------------------
// zp volume: BTOT*16zq*512y*512x words = 8,388,608 words (33.5MB)
#define W_ZP    0
#define ZP_WORDS (BTOT * ZQN * HVOL * WVOL)
#define W_PHASE (ZP_WORDS + 16)                    // 1 word (memset per launch)
#define W_BCNT  (W_PHASE + 32)                     // 16 x 1024
#define W_PID   (W_BCNT + SORT_BLOCKS * NBUCKET)
#define W_C0    (W_PID  + TOTAL_PATCHES)
#define W_C1    (W_C0   + TOTAL_PATCHES)
#define W_C2    (W_C1   + TOTAL_PATCHES)

// 16-byte access with only 4-byte alignment guarantee.
struct __attribute__((packed, aligned(4))) u4p { unsigned x, y, z, w; };

// ---------------------------------------------------------------------------
// K1, two INDEPENDENT roles (no cross-role sync):
//  blocks [0,16):   global counting sort by (b, z/2, y/32)  [R13-proven]
//  blocks [16,528): build z-quad-packed byte volume zp[b][zq][y][x]
//                   (word = 4 z-bytes at (y,x)), + proto broadcast.
// ---------------------------------------------------------------------------
__global__ __launch_bounds__(512) void k1_kernel(
    const int*   __restrict__ seg,
    const float* __restrict__ coords,
    const float* __restrict__ proto,
    float*       __restrict__ out,
    unsigned*    __restrict__ ws)
{
    const int bid = (int)blockIdx.x;
    const int t   = (int)threadIdx.x;

    if (bid >= SORT_BLOCKS) {
        // ---------------- role 1: z-quad pack build -------------------------
        const int gid0 = (bid - SORT_BLOCKS) * 512 + t;

        if (gid0 < RF_N)                     // proto broadcast (output 0)
            out[gid0] = proto[gid0 >= PROTO_N ? gid0 - PROTO_N : gid0];

#pragma unroll
        for (int it = 0; it < 8; ++it) {
            const int g  = gid0 + it * (BUILD_BLOCKS * 512);
            const int xg = g & 127;                  // 4-x group
            const int y  = (g >> 7) & 511;
            const int zq = (g >> 16) & 15;
            const int b  = g >> 20;

            const int srow = b * DHW_ + y * WVOL + xg * 4;
            const int4 v0 = *(const int4*)(seg + srow + (zq * 4 + 0) * HW_);
            const int4 v1 = *(const int4*)(seg + srow + (zq * 4 + 1) * HW_);
            const int4 v2 = *(const int4*)(seg + srow + (zq * 4 + 2) * HW_);
            const int4 v3 = *(const int4*)(seg + srow + (zq * 4 + 3) * HW_);

            uint4 w;
            w.x = (unsigned)v0.x | ((unsigned)v1.x << 8)
                | ((unsigned)v2.x << 16) | ((unsigned)v3.x << 24);
            w.y = (unsigned)v0.y | ((unsigned)v1.y << 8)
                | ((unsigned)v2.y << 16) | ((unsigned)v3.y << 24);
            w.z = (unsigned)v0.z | ((unsigned)v1.z << 8)
                | ((unsigned)v2.z << 16) | ((unsigned)v3.z << 24);
            w.w = (unsigned)v0.w | ((unsigned)v1.w << 8)
                | ((unsigned)v2.w << 16) | ((unsigned)v3.w << 24);

            ((uint4*)(ws + W_ZP))[((b * ZQN + zq) * HVOL + y) * 128 + xg] = w;
        }
        return;
    }

    // ---------------- role 0: counting sort (R13-proven) --------------------
    __shared__ unsigned hist[NBUCKET];
    __shared__ unsigned sA[NBUCKET], sB[NBUCKET];
    __shared__ unsigned curs[NBUCKET];

    float* wsf = (float*)ws;
    const int blk = bid;                   // 0..15
    const int p0  = blk * 2048 + t * 4;
    const int b   = blk >> 3;

    hist[t] = 0u; hist[t + 512] = 0u;
    __syncthreads();

    float c[12];
    {
        const float4* cp = (const float4*)(coords + (size_t)p0 * 3);
        const float4 a = cp[0], bb = cp[1], d = cp[2];
        c[0]=a.x;  c[1]=a.y;  c[2]=a.z;  c[3]=a.w;  c[4]=bb.x; c[5]=bb.y;
        c[6]=bb.z; c[7]=bb.w; c[8]=d.x;  c[9]=d.y;  c[10]=d.z; c[11]=d.w;
    }
    unsigned key[4];
#pragma unroll
    for (int i = 0; i < 4; ++i) {
        const int zbin = ((int)(c[3*i + 0] * 64.0f))  >> 1;
        const int ybin = ((int)(c[3*i + 1] * 512.0f)) >> 5;
        key[i] = (unsigned)(b * 512 + zbin * 16 + ybin);
        atomicAdd(&hist[key[i]], 1u);
    }
    __syncthreads();

    ws[W_BCNT + blk * NBUCKET + t]       = hist[t];
    ws[W_BCNT + blk * NBUCKET + t + 512] = hist[t + 512];
    __syncthreads();

    if (t == 0) {
        __hip_atomic_fetch_add(&ws[W_PHASE], 1u,
                               __ATOMIC_RELEASE, __HIP_MEMORY_SCOPE_AGENT);
        int guard = 0;
        while (__hip_atomic_load(&ws[W_PHASE],
                 __ATOMIC_ACQUIRE, __HIP_MEMORY_SCOPE_AGENT) < SORT_BLOCKS
               && guard < (1 << 24)) {
            __builtin_amdgcn_s_sleep(1);
            ++guard;
        }
    }
    __syncthreads();

    unsigned tot0 = 0u, bef0 = 0u, tot1 = 0u, bef1 = 0u;
#pragma unroll
    for (int k = 0; k < SORT_BLOCKS; ++k) {
        const unsigned v0 = ws[W_BCNT + k * NBUCKET + t];
        const unsigned v1 = ws[W_BCNT + k * NBUCKET + t + 512];
        tot0 += v0; bef0 += (k < blk) ? v0 : 0u;
        tot1 += v1; bef1 += (k < blk) ? v1 : 0u;
    }
    sA[t] = tot0; sA[t + 512] = tot1;
    __syncthreads();

    unsigned* src = sA;
    unsigned* dst = sB;
    for (int off = 1; off < NBUCKET; off <<= 1) {
        dst[t]       = src[t]       + ((t       >= off) ? src[t       - off] : 0u);
        dst[t + 512] = src[t + 512] + ((t + 512 >= off) ? src[t + 512 - off] : 0u);
        __syncthreads();
        unsigned* tmp = src; src = dst; dst = tmp;
    }
    curs[t]       = (src[t]       - tot0) + bef0;
    curs[t + 512] = (src[t + 512] - tot1) + bef1;
    __syncthreads();

#pragma unroll
    for (int i = 0; i < 4; ++i) {
        const unsigned rank = atomicAdd(&curs[key[i]], 1u);
        ws[W_PID + rank] = (unsigned)(p0 + i);
        wsf[W_C0 + rank] = c[3*i + 0];
        wsf[W_C1 + rank] = c[3*i + 1];
        wsf[W_C2 + rank] = c[3*i + 2];
    }
}

// ---------------------------------------------------------------------------
// K2: one wave per sorted slot, reading the z-quad-packed volume.
// Lane (yy=lane>>2, xl4=lane&3): per plane one u4p load = 4 x-words
// (4x x 4z bytes). Funnel-shift plane pair by (sz&3)*8 -> each word holds
// exactly the 4-byte z-window for its x. 2 loads, ~34 row-touches (vs 77).
// ---------------------------------------------------------------------------
__global__ __launch_bounds__(256) void assign_kernel(
    const unsigned* __restrict__ ws,
    float*          __restrict__ out)
{
    const float* wsf = (const float*)ws;

    const int bid  = (int)blockIdx.x;
    const int sbid = (bid & 7) * 1024 + (bid >> 3);

    const int lane = threadIdx.x & 63;
    const int wave = threadIdx.x >> 6;
    const int slot = sbid * 4 + wave;

    const int   patch = (int)ws[W_PID + slot];        // wave-uniform
    const float c0 = wsf[W_C0 + slot] * 64.0f;        // z
    const float c1 = wsf[W_C1 + slot] * 512.0f;       // y
    const float c2 = wsf[W_C2 + slot] * 512.0f;       // x
    const int b = patch >> 14;

    const int sz = (int)fmaxf(0.0f,   floorf(c0 - 2.0f));
    const int ez = (int)fminf(64.0f,  floorf(c0 + 2.0f));
    const int sy = (int)fmaxf(0.0f,   floorf(c1 - 8.0f));
    const int ey = (int)fminf(512.0f, floorf(c1 + 8.0f));
    const int sx = (int)fmaxf(0.0f,   floorf(c2 - 8.0f));
    const int ex = (int)fminf(512.0f, floorf(c2 + 8.0f));

    const int zq0 = sz >> 2;
    const int s0  = sz & 3;
    const int zq1 = min(zq0 + 1, ZQN - 1);
    const int sh  = s0 * 8;

    const int xl4  = lane & 3;
    const int yy   = lane >> 2;
    const int p_lo = sx + 4 * xl4;              // intended word start (x)
    const int st   = min(p_lo, WVOL - 4);       // clamped in-row
    const int yi   = sy + yy;
    const int vy   = (yi < ey) ? 1 : 0;
    const int yiC  = min(yi, HVOL - 1);

    const unsigned* zp = ws + W_ZP;
    const int row0 = ((b * ZQN + zq0) * HVOL + yiC) * WVOL + st;
    const int row1 = ((b * ZQN + zq1) * HVOL + yiC) * WVOL + st;

    // two unconditional 16B loads, back-to-back
    const u4p q0 = *(const u4p*)(zp + row0);
    const u4p q1 = *(const u4p*)(zp + row1);

    // z-window byte mask: bytes [0, zlen)
    const int zlen = min(ez - sz, 4);
    const unsigned zm = (zlen >= 4) ? 0xFFFFFFFFu
                      : (zlen <= 0) ? 0u : ((1u << (8 * zlen)) - 1u);

    // funnel-shift each word pair -> z-window bytes; mask x/y/z validity
    unsigned wrd[4];
    {
        const unsigned a[4] = {q0.x, q0.y, q0.z, q0.w};
        const unsigned bq[4] = {q1.x, q1.y, q1.z, q1.w};
#pragma unroll
        for (int j = 0; j < 4; ++j) {
            const int pos = st + j;
            const unsigned xv = (pos >= p_lo && pos < ex && vy) ? 0xFFFFFFFFu : 0u;
            const unsigned f = (a[j] >> sh) | (sh ? (bq[j] << (32 - sh)) : 0u);
            wrd[j] = f & zm & xv;
        }
    }

    // packed 8-bit histogram: cc[k] holds regions 4k..4k+3 (0-based m)
    unsigned cc[5] = {0u, 0u, 0u, 0u, 0u};
#pragma unroll
    for (int j = 0; j < 4; ++j) {
        const unsigned x = wrd[j];
#pragma unroll
        for (int jj = 0; jj < 4; ++jj) {
            const int v = (int)((x >> (8 * jj)) & 0xFFu);
            const int tt = v - 1;                      // -1 if not counted
            const unsigned inc = 1u << ((tt & 3) << 3);
            const int qk = tt >> 2;                    // -1 matches no k
#pragma unroll
            for (int k = 0; k < 5; ++k)
                cc[k] += (qk == k) ? inc : 0u;
        }
    }

    // 3-step packed butterfly (8-lane groups; per-lane max 16 -> <=128/field)
#pragma unroll
    for (int off = 1; off < 8; off <<= 1) {
#pragma unroll
        for (int k = 0; k < 5; ++k)
            cc[k] += (unsigned)__shfl_xor((int)cc[k], off);
    }

    // unpack 8-bit -> 2x16-bit, 3 more steps across the 8 groups
    unsigned lo[5], hi[5];
#pragma unroll
    for (int k = 0; k < 5; ++k) {
        lo[k] = cc[k] & 0x00FF00FFu;          // regions 4k (lo16), 4k+2 (hi16)
        hi[k] = (cc[k] >> 8) & 0x00FF00FFu;   // regions 4k+1,      4k+3
    }
#pragma unroll
    for (int off = 8; off < 64; off <<= 1) {
#pragma unroll
        for (int k = 0; k < 5; ++k) {
            lo[k] += (unsigned)__shfl_xor((int)lo[k], off);
            hi[k] += (unsigned)__shfl_xor((int)hi[k], off);
        }
    }

    unsigned S = 0u;
#pragma unroll
    for (int k = 0; k < 5; ++k) S += lo[k] + hi[k];
    const unsigned tot = (S & 0xFFFFu) + (S >> 16);   // <= 1024, no carry

    const int r = lane & 3;
    const unsigned sLo = (lane < 4) ? lo[0] : (lane < 8) ? lo[1]
                       : (lane < 12) ? lo[2] : (lane < 16) ? lo[3] : lo[4];
    const unsigned sHi = (lane < 4) ? hi[0] : (lane < 8) ? hi[1]
                       : (lane < 12) ? hi[2] : (lane < 16) ? hi[3] : hi[4];
    const unsigned fld = (r & 1) ? sHi : sLo;
    const unsigned cnt = (r & 2) ? (fld >> 16) : (fld & 0xFFFFu);

    if (lane < NREG) {
        const float nz = (float)max(ez - sz, 0);
        const float ny = (float)max(ey - sy, 0);
        const float nx = (float)max(ex - sx, 0);
        const float denom = fmaxf(nz * ny * nx, 1.0f);
        const float s = (float)tot / denom + (float)NREG * 1e-6f;
        const float a = (float)cnt / denom + 1e-6f;
        out[RF_N + patch * NREG + lane] = a / s;
    }
}

// ---------------------------------------------------------------------------
extern "C" void kernel_launch(void* const* d_in, const int* in_sizes, int n_in,
                              void* d_out, int out_size, void* d_ws, size_t ws_size,
                              hipStream_t stream)
{
    const int*   seg    = (const int*)d_in[0];
    const float* coords = (const float*)d_in[1];
    const float* proto  = (const float*)d_in[2];
    float*       out    = (float*)d_out;
    unsigned*    ws     = (unsigned*)d_ws;

    hipMemsetAsync(ws + W_PHASE, 0, sizeof(unsigned), stream);  // phase only
    hipLaunchKernelGGL(k1_kernel, dim3(K1_BLOCKS), dim3(512),
                       0, stream, seg, coords, proto, out, ws);
    hipLaunchKernelGGL(assign_kernel, dim3(TOTAL_PATCHES / 4), dim3(256),
                       0, stream, ws, out);
}

// Round 15
// 48.791 us; speedup vs baseline: 1.3896x; 1.3896x over previous
//
#include <hip/hip_runtime.h>
#include <stdint.h>

#define NREG   20
#define EDIM   768
#define DVOL   64
#define HVOL   512
#define WVOL   512
#define HW_    (HVOL * WVOL)
#define DHW_   (DVOL * HVOL * WVOL)
#define NPATCH 16384
#define BTOT   2
#define PROTO_N (NREG * EDIM)            // 15360
#define RF_N    (BTOT * PROTO_N)         // 30720 floats (output 0)
#define TOTAL_PATCHES (BTOT * NPATCH)    // 32768
#define NBUCKET 1024                     // 2 b x 32 zbins x 16 ybins
#define SORT_BLOCKS 16                   // co-resident by capacity -> safe spin

// workspace layout (u32 words)
#define W_PHASE 0                        // 1 word (zeroed by memset each launch)
#define W_BCNT  32                       // 16 x 1024 per-block bucket counts
#define W_PID   (W_BCNT + SORT_BLOCKS * NBUCKET)
#define W_C0    (W_PID  + TOTAL_PATCHES)
#define W_C1    (W_C0   + TOTAL_PATCHES)
#define W_C2    (W_C1   + TOTAL_PATCHES)

// 16-byte load with only 4-byte alignment guarantee.
struct __attribute__((packed, aligned(4))) int4p { int x, y, z, w; };

// ---------------------------------------------------------------------------
// Single-dispatch global counting sort (R13-proven role, standalone):
// 16 blocks x 512 threads; block owns 2048 consecutive patches.
//   1) LDS histogram -> bcnt[blk][*]
//   2) agent-scope phase barrier (16 blocks co-resident by capacity)
//   3) redundant per-block totals + scan + base cursors
//   4) scatter pid + SoA coords via LDS cursor atomics
// ---------------------------------------------------------------------------
__global__ __launch_bounds__(512) void sort_kernel(
    const float* __restrict__ coords, unsigned* __restrict__ ws)
{
    __shared__ unsigned hist[NBUCKET];
    __shared__ unsigned sA[NBUCKET], sB[NBUCKET];
    __shared__ unsigned curs[NBUCKET];

    float* wsf = (float*)ws;
    const int blk = (int)blockIdx.x;       // 0..15
    const int t   = (int)threadIdx.x;      // 0..511
    const int p0  = blk * 2048 + t * 4;    // 4 consecutive patches per thread
    const int b   = blk >> 3;              // batch (uniform per block)

    hist[t] = 0u; hist[t + 512] = 0u;
    __syncthreads();

    // 4 patches: 12 contiguous floats (48B, 16B-aligned since p0 % 4 == 0)
    float c[12];
    {
        const float4* cp = (const float4*)(coords + (size_t)p0 * 3);
        const float4 a = cp[0], bb = cp[1], d = cp[2];
        c[0]=a.x;  c[1]=a.y;  c[2]=a.z;  c[3]=a.w;  c[4]=bb.x; c[5]=bb.y;
        c[6]=bb.z; c[7]=bb.w; c[8]=d.x;  c[9]=d.y;  c[10]=d.z; c[11]=d.w;
    }
    unsigned key[4];
#pragma unroll
    for (int i = 0; i < 4; ++i) {
        const int zbin = ((int)(c[3*i + 0] * 64.0f))  >> 1;   // 0..31
        const int ybin = ((int)(c[3*i + 1] * 512.0f)) >> 5;   // 0..15
        key[i] = (unsigned)(b * 512 + zbin * 16 + ybin);
        atomicAdd(&hist[key[i]], 1u);
    }
    __syncthreads();

    ws[W_BCNT + blk * NBUCKET + t]       = hist[t];
    ws[W_BCNT + blk * NBUCKET + t + 512] = hist[t + 512];
    __syncthreads();

    if (t == 0) {
        __hip_atomic_fetch_add(&ws[W_PHASE], 1u,
                               __ATOMIC_RELEASE, __HIP_MEMORY_SCOPE_AGENT);
        int guard = 0;
        while (__hip_atomic_load(&ws[W_PHASE],
                 __ATOMIC_ACQUIRE, __HIP_MEMORY_SCOPE_AGENT) < SORT_BLOCKS
               && guard < (1 << 24)) {
            __builtin_amdgcn_s_sleep(1);
            ++guard;
        }
    }
    __syncthreads();

    // totals + this block's "before" share, for buckets t and t+512
    unsigned tot0 = 0u, bef0 = 0u, tot1 = 0u, bef1 = 0u;
#pragma unroll
    for (int k = 0; k < SORT_BLOCKS; ++k) {
        const unsigned v0 = ws[W_BCNT + k * NBUCKET + t];
        const unsigned v1 = ws[W_BCNT + k * NBUCKET + t + 512];
        tot0 += v0; bef0 += (k < blk) ? v0 : 0u;
        tot1 += v1; bef1 += (k < blk) ? v1 : 0u;
    }
    sA[t] = tot0; sA[t + 512] = tot1;
    __syncthreads();

    // inclusive Hillis-Steele scan over 1024 buckets (double-buffered)
    unsigned* src = sA;
    unsigned* dst = sB;
    for (int off = 1; off < NBUCKET; off <<= 1) {
        dst[t]       = src[t]       + ((t       >= off) ? src[t       - off] : 0u);
        dst[t + 512] = src[t + 512] + ((t + 512 >= off) ? src[t + 512 - off] : 0u);
        __syncthreads();
        unsigned* tmp = src; src = dst; dst = tmp;
    }
    curs[t]       = (src[t]       - tot0) + bef0;   // exclusive + block base
    curs[t + 512] = (src[t + 512] - tot1) + bef1;
    __syncthreads();

    // scatter own 4 patches (pid + SoA coords)
#pragma unroll
    for (int i = 0; i < 4; ++i) {
        const unsigned rank = atomicAdd(&curs[key[i]], 1u);
        ws[W_PID + rank] = (unsigned)(p0 + i);
        wsf[W_C0 + rank] = c[3*i + 0];
        wsf[W_C1 + rank] = c[3*i + 1];
        wsf[W_C2 + rank] = c[3*i + 2];
    }
}

// ---------------------------------------------------------------------------
// Assign (R12-proven, empirical best): one wave per globally-sorted slot,
// XCD swizzle -> each XCD sweeps a contiguous spatial slice. 4 unconditional
// int4 gathers, packed 8-bit histogram, shfl butterfly, in-register finish.
// Blocks 0..119 also copy the prototype broadcast (output 0).
// ---------------------------------------------------------------------------
__global__ __launch_bounds__(256) void assign_kernel(
    const int*      __restrict__ seg,
    const unsigned* __restrict__ ws,
    const float*    __restrict__ proto,
    float*          __restrict__ out)
{
    if (blockIdx.x < RF_N / 256) {
        const int i = (int)blockIdx.x * 256 + (int)threadIdx.x;
        out[i] = proto[i >= PROTO_N ? i - PROTO_N : i];
    }

    const int bid  = (int)blockIdx.x;
    const int sbid = (bid & 7) * 1024 + (bid >> 3);

    const int lane = threadIdx.x & 63;
    const int wave = threadIdx.x >> 6;
    const int slot = sbid * 4 + wave;

    const int   patch = (int)ws[W_PID + slot];                  // uniform
    const float c0 = ((const float*)ws)[W_C0 + slot] * 64.0f;   // z
    const float c1 = ((const float*)ws)[W_C1 + slot] * 512.0f;  // y
    const float c2 = ((const float*)ws)[W_C2 + slot] * 512.0f;  // x
    const int b = patch >> 14;

    const int sz = (int)fmaxf(0.0f,   floorf(c0 - 2.0f));
    const int ez = (int)fminf(64.0f,  floorf(c0 + 2.0f));
    const int sy = (int)fmaxf(0.0f,   floorf(c1 - 8.0f));
    const int ey = (int)fminf(512.0f, floorf(c1 + 8.0f));
    const int sx = (int)fmaxf(0.0f,   floorf(c2 - 8.0f));
    const int ex = (int)fminf(512.0f, floorf(c2 + 8.0f));

    const int xl4  = lane & 3;
    const int yy   = lane >> 2;
    const int p_lo = sx + 4 * xl4;
    const int st   = min(p_lo, WVOL - 4);
    const int yi   = sy + yy;
    const unsigned vy = (yi < ey) ? 0xFFFFFFFFu : 0u;
    const int yiC  = min(yi, HVOL - 1);
    const int rowbase = b * DHW_ + yiC * WVOL + st;

    unsigned vm[4];
#pragma unroll
    for (int j = 0; j < 4; ++j) {
        const int pos = st + j;
        vm[j] = (pos >= p_lo && pos < ex) ? vy : 0u;
    }

    int4p q0, q1, q2, q3;
    {
        const int z0 = min(sz + 0, DVOL - 1) * HW_;
        const int z1 = min(sz + 1, DVOL - 1) * HW_;
        const int z2 = min(sz + 2, DVOL - 1) * HW_;
        const int z3 = min(sz + 3, DVOL - 1) * HW_;
        q0 = *(const int4p*)(seg + rowbase + z0);
        q1 = *(const int4p*)(seg + rowbase + z1);
        q2 = *(const int4p*)(seg + rowbase + z2);
        q3 = *(const int4p*)(seg + rowbase + z3);
    }

    unsigned cc[5] = {0u, 0u, 0u, 0u, 0u};
#pragma unroll
    for (int z = 0; z < 4; ++z) {
        const unsigned zm = (sz + z < ez) ? 0xFFFFFFFFu : 0u;
        const int4p qz = (z == 0) ? q0 : (z == 1) ? q1 : (z == 2) ? q2 : q3;
        const int vals[4] = {qz.x, qz.y, qz.z, qz.w};
#pragma unroll
        for (int j = 0; j < 4; ++j) {
            const int v = vals[j] & (int)(vm[j] & zm);   // invalid -> 0
            const int t = v - 1;                         // -1 if not counted
            const unsigned inc = 1u << ((t & 3) << 3);
            const int qk = t >> 2;                       // -1 matches no k
#pragma unroll
            for (int k = 0; k < 5; ++k)
                cc[k] += (qk == k) ? inc : 0u;
        }
    }

#pragma unroll
    for (int off = 1; off < 8; off <<= 1) {
#pragma unroll
        for (int k = 0; k < 5; ++k)
            cc[k] += (unsigned)__shfl_xor((int)cc[k], off);
    }

    unsigned lo[5], hi[5];
#pragma unroll
    for (int k = 0; k < 5; ++k) {
        lo[k] = cc[k] & 0x00FF00FFu;          // regions 4k (lo16), 4k+2 (hi16)
        hi[k] = (cc[k] >> 8) & 0x00FF00FFu;   // regions 4k+1,      4k+3
    }
#pragma unroll
    for (int off = 8; off < 64; off <<= 1) {
#pragma unroll
        for (int k = 0; k < 5; ++k) {
            lo[k] += (unsigned)__shfl_xor((int)lo[k], off);
            hi[k] += (unsigned)__shfl_xor((int)hi[k], off);
        }
    }

    unsigned S = 0u;
#pragma unroll
    for (int k = 0; k < 5; ++k) S += lo[k] + hi[k];
    const unsigned tot = (S & 0xFFFFu) + (S >> 16);   // <= 1024, no carry

    const int r = lane & 3;
    const unsigned sLo = (lane < 4) ? lo[0] : (lane < 8) ? lo[1]
                       : (lane < 12) ? lo[2] : (lane < 16) ? lo[3] : lo[4];
    const unsigned sHi = (lane < 4) ? hi[0] : (lane < 8) ? hi[1]
                       : (lane < 12) ? hi[2] : (lane < 16) ? hi[3] : hi[4];
    const unsigned fld = (r & 1) ? sHi : sLo;
    const unsigned cnt = (r & 2) ? (fld >> 16) : (fld & 0xFFFFu);

    if (lane < NREG) {
        const float nz = (float)max(ez - sz, 0);
        const float ny = (float)max(ey - sy, 0);
        const float nx = (float)max(ex - sx, 0);
        const float denom = fmaxf(nz * ny * nx, 1.0f);
        const float s = (float)tot / denom + (float)NREG * 1e-6f;
        const float a = (float)cnt / denom + 1e-6f;
        out[RF_N + patch * NREG + lane] = a / s;
    }
}

// ---------------------------------------------------------------------------
extern "C" void kernel_launch(void* const* d_in, const int* in_sizes, int n_in,
                              void* d_out, int out_size, void* d_ws, size_t ws_size,
                              hipStream_t stream)
{
    const int*   seg    = (const int*)d_in[0];
    const float* coords = (const float*)d_in[1];
    const float* proto  = (const float*)d_in[2];
    float*       out    = (float*)d_out;
    unsigned*    ws     = (unsigned*)d_ws;

    hipMemsetAsync(ws, 0, sizeof(unsigned), stream);   // phase word only
    hipLaunchKernelGGL(sort_kernel, dim3(SORT_BLOCKS), dim3(512),
                       0, stream, coords, ws);
    hipLaunchKernelGGL(assign_kernel, dim3(TOTAL_PATCHES / 4), dim3(256),
                       0, stream, seg, ws, proto, out);
}